// Round 7
// baseline (178.688 us; speedup 1.0000x reference)
//
#include <hip/hip_runtime.h>

// Problem dims (from reference setup_inputs)
#define BB 4
#define CC 64
#define HH 256
#define WW 256
#define NPIX (HH*WW)          // 65536
#define NCLS 4
#define NPAIR 12              // B*(NCLS-1)
#define HALF 512
#define MAXS 1024
#define NOUT (NPAIR*CC*MAXS)  // 786432
#define CHUNK 4096
#define NCHUNK (NPIX/CHUNK)   // 16
#define NBAND 64              // 4-row bands per image
#define MAGIC 0x5F3C9A1Bu
#define NB_A 256              // dargmax blocks
#define NB_B 192              // assign blocks
#define NB_C 768              // gather blocks (pair x channel)
#define NBLK (NB_A + NB_B + NB_C)   // 1216

// ---------------------------------------------------------------------------
// Single dispatch, three phases chained by one-way producer->consumer flags
// (agent-scope release/acquire). No rendezvous: producers never wait, waiters
// s_sleep-poll. Deadlock-free by construction (dependency is one-way by block
// index; all 4864 waves fit the 8192-wave machine anyway). Flags need no
// zero-init: harness poison 0xAAAAAAAA != MAGIC; each call re-stores MAGIC.
// Phase bodies are the round-5 kernels verbatim (verified absmax = 0).
// ---------------------------------------------------------------------------
__global__ void __launch_bounds__(256) k_fused(
        const float* __restrict__ feat, const int* __restrict__ labels,
        const float* __restrict__ preds, float* __restrict__ out,
        unsigned char* __restrict__ pd, unsigned* __restrict__ bandCounts,
        unsigned* __restrict__ pairTotals, int* __restrict__ slots,
        unsigned* __restrict__ imgFlags, unsigned* __restrict__ pairFlags) {
    int bx = blockIdx.x;
    int t = threadIdx.x;

    __shared__ unsigned char vm[4][WW];
    __shared__ unsigned wsum[4][3];
    __shared__ unsigned bc[NBAND];
    __shared__ unsigned ws[4];

    if (bx < NB_A) {
        // ---- Phase A: argmax + separable 3x3 dilation + per-band counts ----
        int b = bx >> 6, band = bx & 63;
        int y0 = band * 4;
        int x = t;
        const float* pb = preds + (size_t)b * NCLS * NPIX;
        unsigned char am[6];
#pragma unroll
        for (int r = 0; r < 6; ++r) {
            int y = y0 + r - 1;
            unsigned char a = 0;
            if (y >= 0 && y < HH) {
                const float* p = pb + y * WW + x;
                float best = p[0];
                int arg = 0;
#pragma unroll
                for (int c = 1; c < NCLS; ++c) {
                    float v = p[(size_t)c * NPIX];
                    if (v > best) { best = v; arg = c; }   // first-max wins (jnp.argmax)
                }
                a = (unsigned char)arg;
            }
            am[r] = a;
        }
        unsigned char vmr[4];
#pragma unroll
        for (int ry = 0; ry < 4; ++ry) {
            int m = am[ry];
            if (am[ry + 1] > m) m = am[ry + 1];
            if (am[ry + 2] > m) m = am[ry + 2];
            vmr[ry] = (unsigned char)m;
            vm[ry][x] = (unsigned char)m;
        }
        __syncthreads();
        unsigned pk[3] = {0u, 0u, 0u};
#pragma unroll
        for (int ry = 0; ry < 4; ++ry) {
            int m = vmr[ry];
            if (x > 0)      { int v = vm[ry][x - 1]; if (v > m) m = v; }
            if (x < WW - 1) { int v = vm[ry][x + 1]; if (v > m) m = v; }
            int idx = b * NPIX + (y0 + ry) * WW + x;
            pd[idx] = (unsigned char)m;
            int l = labels[idx];
#pragma unroll
            for (int c = 0; c < 3; ++c)
                if (l == c + 1) pk[c] += (m == c + 1) ? (1u << 16) : 1u;
        }
        int lane = x & 63, w = x >> 6;
#pragma unroll
        for (int c = 0; c < 3; ++c)
#pragma unroll
            for (int off = 32; off > 0; off >>= 1)
                pk[c] += (unsigned)__shfl_down((int)pk[c], off, 64);
        if (lane == 0) { wsum[w][0] = pk[0]; wsum[w][1] = pk[1]; wsum[w][2] = pk[2]; }
        __syncthreads();
        if (x < 3)
            bandCounts[(b * 3 + x) * NBAND + band] =
                wsum[0][x] + wsum[1][x] + wsum[2][x] + wsum[3][x];
        __syncthreads();
        if (x == 0)
            __hip_atomic_store(&imgFlags[b * NBAND + band], MAGIC,
                               __ATOMIC_RELEASE, __HIP_MEMORY_SCOPE_AGENT);

    } else if (bx < NB_A + NB_B) {
        // ---- Phase B: slot assignment for (pair, chunk) ----
        int k = bx - NB_A;
        int pair = k >> 4, chunk = k & 15;
        int b = pair / 3, cls = pair % 3 + 1;

        // wait for all 64 bands of image b (pd rows + counts)
        if (t < NBAND) {
            while (__hip_atomic_load(&imgFlags[b * NBAND + t],
                                     __ATOMIC_ACQUIRE, __HIP_MEMORY_SCOPE_AGENT) != MAGIC)
                __builtin_amdgcn_s_sleep(8);
        }
        __syncthreads();

        if (t < NBAND) bc[t] = bandCounts[pair * NBAND + t];
        __syncthreads();
        unsigned base = 0, total = 0;
        int cut = chunk * 4;
#pragma unroll
        for (int i = 0; i < NBAND; ++i) {
            unsigned v = bc[i];
            total += v;
            if (i < cut) base += v;
        }
        if (chunk == 0 && t == 0) {
            pairTotals[pair] = total;
            out[NOUT + pair] = (float)cls;        // feat_label
        }
        int excess = (int)(total & 0xffffu) - HALF;
        if (excess < 0) excess = 0;
        int baseH = (int)(base & 0xffffu), baseE = (int)(base >> 16);
        if (!(baseH >= MAXS && HALF + excess + baseE >= MAXS)) {   // block-uniform
            const int4* lab4 = (const int4*)(labels + b * NPIX + chunk * CHUNK + t * 16);
            const uint4* pd16 = (const uint4*)(pd + b * NPIX + chunk * CHUNK + t * 16);
            int4 l0 = lab4[0], l1 = lab4[1], l2 = lab4[2], l3 = lab4[3];
            uint4 dp = pd16[0];
            int ls[16] = {l0.x, l0.y, l0.z, l0.w, l1.x, l1.y, l1.z, l1.w,
                          l2.x, l2.y, l2.z, l2.w, l3.x, l3.y, l3.z, l3.w};
            unsigned char ds[16];
            unsigned dw[4] = {dp.x, dp.y, dp.z, dp.w};
#pragma unroll
            for (int j = 0; j < 16; ++j) ds[j] = (dw[j >> 2] >> ((j & 3) * 8)) & 0xff;

            unsigned mine = 0;
#pragma unroll
            for (int j = 0; j < 16; ++j)
                if (ls[j] == cls) mine += (ds[j] == cls) ? (1u << 16) : 1u;

            int lane = t & 63, w = t >> 6;
            unsigned v = mine;
#pragma unroll
            for (int off = 1; off < 64; off <<= 1) {
                unsigned u = (unsigned)__shfl_up((int)v, off, 64);
                if (lane >= off) v += u;
            }
            if (lane == 63) ws[w] = v;
            __syncthreads();
            unsigned waveBase = 0;
            for (int i = 0; i < w; ++i) waveBase += ws[i];
            unsigned excl = waveBase + v - mine;

            int hr = baseH + (int)(excl & 0xffffu);
            int er = baseE + (int)(excl >> 16);
            int pixBase = chunk * CHUNK + t * 16;
            int* sl = slots + pair * MAXS;
#pragma unroll
            for (int j = 0; j < 16; ++j) {
                if (ls[j] == cls) {
                    if (ds[j] != cls) {
                        if (hr < MAXS) sl[hr] = pixBase + j;
                        hr++;
                    } else {
                        int pos = HALF + excess + er;
                        if (pos < MAXS) sl[pos] = pixBase + j;
                        er++;
                    }
                }
            }
        }
        __syncthreads();
        if (t == 0)
            __hip_atomic_store(&pairFlags[pair * NCHUNK + chunk], MAGIC,
                               __ATOMIC_RELEASE, __HIP_MEMORY_SCOPE_AGENT);

    } else {
        // ---- Phase C: gather one (pair, channel); 4 slots/thread ----
        int i = bx - NB_A - NB_B;            // [0, 768)
        int pair = i >> 6, c = i & 63;
        int b = pair / 3;

        if (t < NCHUNK) {
            while (__hip_atomic_load(&pairFlags[pair * NCHUNK + t],
                                     __ATOMIC_ACQUIRE, __HIP_MEMORY_SCOPE_AGENT) != MAGIC)
                __builtin_amdgcn_s_sleep(8);
        }
        __syncthreads();

        unsigned tot = pairTotals[pair];
        int Nh = (int)(tot & 0xffffu), Ne = (int)(tot >> 16);
        int excess = Nh - HALF; if (excess < 0) excess = 0;
        int hardEnd = Nh < MAXS ? Nh : MAXS;
        int easyStart = HALF + excess;
        int easyEnd = easyStart + Ne; if (easyEnd > MAXS) easyEnd = MAXS;

        int slot = t * 4;
        const float* fp = feat + ((size_t)(b * CC + c)) * NPIX;
        const int* sp = slots + pair * MAXS + slot;
        float o[4];
#pragma unroll
        for (int j = 0; j < 4; ++j) {
            int s = slot + j;
            bool valid = (s < hardEnd) || (s >= easyStart && s < easyEnd);
            float val = 0.0f;
            if (valid) val = fp[sp[j]];      // poisoned entries never dereferenced
            o[j] = val;
        }
        float* ob = out + ((size_t)pair * CC + c) * MAXS + slot;
        *(float4*)ob = make_float4(o[0], o[1], o[2], o[3]);
    }
}

extern "C" void kernel_launch(void* const* d_in, const int* in_sizes, int n_in,
                              void* d_out, int out_size, void* d_ws, size_t ws_size,
                              hipStream_t stream) {
    const float* feat   = (const float*)d_in[0];  // [B,C,H,W] fp32
    const int*   labels = (const int*)d_in[1];    // [B,H,W] int32
    const float* preds  = (const float*)d_in[2];  // [B,NCLS,H,W] fp32
    float* out = (float*)d_out;

    // workspace layout (all 4B types after the byte buffer; offsets 16B-aligned)
    unsigned char* pd = (unsigned char*)d_ws;                    // 262144 B
    int* slots = (int*)(pd + BB * NPIX);                         // 12288 ints
    unsigned* bandCounts = (unsigned*)(slots + NPAIR * MAXS);    // 768 uints
    unsigned* pairTotals = bandCounts + NPAIR * NBAND;           // 12 uints
    unsigned* imgFlags   = pairTotals + NPAIR;                   // 256 uints
    unsigned* pairFlags  = imgFlags + BB * NBAND;                // 192 uints

    k_fused<<<NBLK, 256, 0, stream>>>(preds != nullptr ? feat : feat, labels, preds, out,
                                      pd, bandCounts, pairTotals, slots, imgFlags, pairFlags);
}

// Round 8
// 106.407 us; speedup vs baseline: 1.6793x; 1.6793x over previous
//
#include <hip/hip_runtime.h>

// Problem dims (from reference setup_inputs)
#define BB 4
#define CC 64
#define HH 256
#define WW 256
#define NPIX (HH*WW)          // 65536
#define NCLS 4
#define NPAIR 12              // B*(NCLS-1)
#define HALF 512
#define MAXS 1024
#define NOUT (NPAIR*CC*MAXS)  // 786432
#define CHUNK 4096
#define NCHUNK (NPIX/CHUNK)   // 16
#define NBAND 64              // 4-row bands per image
#define BANDPIX (NPIX/NBAND)  // 1024

// ---------------------------------------------------------------------------
// Measured-best structure (round 5, 106.5 us): 3 kernels, 2 launch gaps.
// All cross-phase dependencies ride on kernel-launch boundaries -- measured
// cheaper (~1.5 us) than grid.sync (~20 us/barrier, r4) or agent-scope flag
// polling (catastrophic, r7) on this 8-XCD part.
// ---------------------------------------------------------------------------

// K1: fused argmax + separable 3x3 dilation + per-band hard/easy counting.
// Block = one 4-row x 256-col band (256 blocks). Lane x = threadIdx.x: all
// preds/labels loads are coalesced rows. Vertical 3-max per-column in
// registers; only the horizontal 3-max uses LDS. Counts packed hard|easy<<16
// per class, written once per (pair,band) -> no atomics, no zero-init.
// OOB halo rows use argmax=0 (safe: window always contains the center pixel).
__global__ void __launch_bounds__(256) k_dargmax(
        const float* __restrict__ preds, const int* __restrict__ labels,
        unsigned char* __restrict__ pd, unsigned* __restrict__ bandCounts) {
    __shared__ unsigned char vm[4][WW];
    __shared__ unsigned wsum[4][3];
    int bx = blockIdx.x;
    int b = bx >> 6, band = bx & 63;
    int y0 = band * 4;
    int x = threadIdx.x;
    const float* pb = preds + (size_t)b * NCLS * NPIX;

    unsigned char am[6];
#pragma unroll
    for (int r = 0; r < 6; ++r) {
        int y = y0 + r - 1;
        unsigned char a = 0;
        if (y >= 0 && y < HH) {
            const float* p = pb + y * WW + x;
            float best = p[0];
            int arg = 0;
#pragma unroll
            for (int c = 1; c < NCLS; ++c) {
                float v = p[(size_t)c * NPIX];
                if (v > best) { best = v; arg = c; }   // first-max wins (jnp.argmax)
            }
            a = (unsigned char)arg;
        }
        am[r] = a;
    }
    unsigned char vmr[4];
#pragma unroll
    for (int ry = 0; ry < 4; ++ry) {
        int m = am[ry];
        if (am[ry + 1] > m) m = am[ry + 1];
        if (am[ry + 2] > m) m = am[ry + 2];
        vmr[ry] = (unsigned char)m;
        vm[ry][x] = (unsigned char)m;
    }
    __syncthreads();

    unsigned pk[3] = {0u, 0u, 0u};
#pragma unroll
    for (int ry = 0; ry < 4; ++ry) {
        int m = vmr[ry];
        if (x > 0)      { int v = vm[ry][x - 1]; if (v > m) m = v; }
        if (x < WW - 1) { int v = vm[ry][x + 1]; if (v > m) m = v; }
        int idx = b * NPIX + (y0 + ry) * WW + x;
        pd[idx] = (unsigned char)m;
        int l = labels[idx];
#pragma unroll
        for (int c = 0; c < 3; ++c)
            if (l == c + 1) pk[c] += (m == c + 1) ? (1u << 16) : 1u;
    }
    // block reduce the 3 packed counters (fields can't overflow: <= 1024/band)
    int lane = x & 63, w = x >> 6;
#pragma unroll
    for (int c = 0; c < 3; ++c)
#pragma unroll
        for (int off = 32; off > 0; off >>= 1)
            pk[c] += (unsigned)__shfl_down((int)pk[c], off, 64);
    if (lane == 0) { wsum[w][0] = pk[0]; wsum[w][1] = pk[1]; wsum[w][2] = pk[2]; }
    __syncthreads();
    if (x < 3)
        bandCounts[(b * 3 + x) * NBAND + band] =
            wsum[0][x] + wsum[1][x] + wsum[2][x] + wsum[3][x];
}

// K2: slot assignment. Grid (chunk,pair) flattened = 192 blocks, 256 threads,
// 16 contiguous px/thread in registers. Each block redundantly prefix-sums its
// pair's 64 band counts (LDS) for the chunk's base ranks + pair total (absorbs
// a separate scan kernel). Chunk-0 block writes pairTotals + feat_label.
//  hard rank r  -> slot r                 (if r < 1024)
//  easy rank e  -> slot 512 + excess + e  (if < 1024), excess = max(Nh-512,0)
__global__ void __launch_bounds__(256) k_assign(
        const int* __restrict__ labels, const unsigned char* __restrict__ pd,
        const unsigned* __restrict__ bandCounts, unsigned* __restrict__ pairTotals,
        int* __restrict__ slots, float* __restrict__ out) {
    int pair = blockIdx.x >> 4, chunk = blockIdx.x & 15;
    int b = pair / 3, cls = pair % 3 + 1;
    int t = threadIdx.x;
    __shared__ unsigned bc[NBAND];
    __shared__ unsigned ws[4];
    if (t < NBAND) bc[t] = bandCounts[pair * NBAND + t];
    __syncthreads();
    unsigned base = 0, total = 0;
    int cut = chunk * 4;
#pragma unroll
    for (int i = 0; i < NBAND; ++i) {
        unsigned v = bc[i];
        total += v;
        if (i < cut) base += v;
    }
    if (chunk == 0 && t == 0) {
        pairTotals[pair] = total;
        out[NOUT + pair] = (float)cls;        // feat_label
    }
    int excess = (int)(total & 0xffffu) - HALF;
    if (excess < 0) excess = 0;
    int baseH = (int)(base & 0xffffu), baseE = (int)(base >> 16);
    if (baseH >= MAXS && HALF + excess + baseE >= MAXS) return;   // nothing lands

    const int4* lab4 = (const int4*)(labels + b * NPIX + chunk * CHUNK + t * 16);
    const uint4* pd16 = (const uint4*)(pd + b * NPIX + chunk * CHUNK + t * 16);
    int4 l0 = lab4[0], l1 = lab4[1], l2 = lab4[2], l3 = lab4[3];
    uint4 dp = pd16[0];
    int ls[16] = {l0.x, l0.y, l0.z, l0.w, l1.x, l1.y, l1.z, l1.w,
                  l2.x, l2.y, l2.z, l2.w, l3.x, l3.y, l3.z, l3.w};
    unsigned char ds[16];
    unsigned dw[4] = {dp.x, dp.y, dp.z, dp.w};
#pragma unroll
    for (int j = 0; j < 16; ++j) ds[j] = (dw[j >> 2] >> ((j & 3) * 8)) & 0xff;

    unsigned mine = 0;
#pragma unroll
    for (int j = 0; j < 16; ++j)
        if (ls[j] == cls) mine += (ds[j] == cls) ? (1u << 16) : 1u;

    int lane = t & 63, w = t >> 6;
    unsigned v = mine;
#pragma unroll
    for (int off = 1; off < 64; off <<= 1) {
        unsigned u = (unsigned)__shfl_up((int)v, off, 64);
        if (lane >= off) v += u;
    }
    if (lane == 63) ws[w] = v;
    __syncthreads();
    unsigned waveBase = 0;
    for (int i = 0; i < w; ++i) waveBase += ws[i];
    unsigned excl = waveBase + v - mine;

    int hr = baseH + (int)(excl & 0xffffu);
    int er = baseE + (int)(excl >> 16);
    int pixBase = chunk * CHUNK + t * 16;
    int* sl = slots + pair * MAXS;
#pragma unroll
    for (int j = 0; j < 16; ++j) {
        if (ls[j] == cls) {
            if (ds[j] != cls) {
                if (hr < MAXS) sl[hr] = pixBase + j;
                hr++;
            } else {
                int pos = HALF + excess + er;
                if (pos < MAXS) sl[pos] = pixBase + j;
                er++;
            }
        }
    }
}

// K3: gather. Validity computed arithmetically from pairTotals (the exact fill
// intervals of k_assign), so slots[] needs no -1 init; the poisoned entries
// are never dereferenced. 4 consecutive slots/thread, float4 store.
__global__ void __launch_bounds__(256) k_gather(
        const float* __restrict__ feat, const int* __restrict__ slots,
        const unsigned* __restrict__ pairTotals, float* __restrict__ out) {
    int i = blockIdx.x * 256 + threadIdx.x;      // < NOUT/4 = 196608
    int q = i << 2;
    int pair = q >> 16;                          // CC*MAXS = 65536
    unsigned tot = pairTotals[pair];
    int Nh = (int)(tot & 0xffffu), Ne = (int)(tot >> 16);
    int excess = Nh - HALF; if (excess < 0) excess = 0;
    int hardEnd = Nh < MAXS ? Nh : MAXS;
    int easyStart = HALF + excess;
    int easyEnd = easyStart + Ne; if (easyEnd > MAXS) easyEnd = MAXS;

    int c = (q >> 10) & (CC - 1);
    int slot = q & (MAXS - 1);
    int b = pair / 3;
    const float* fp = feat + ((size_t)(b * CC + c)) * NPIX;
    const int* sp = slots + pair * MAXS + slot;
    float o[4];
#pragma unroll
    for (int j = 0; j < 4; ++j) {
        int s = slot + j;
        bool valid = (s < hardEnd) || (s >= easyStart && s < easyEnd);
        float val = 0.0f;
        if (valid) val = fp[sp[j]];
        o[j] = val;
    }
    ((float4*)out)[i] = make_float4(o[0], o[1], o[2], o[3]);
}

extern "C" void kernel_launch(void* const* d_in, const int* in_sizes, int n_in,
                              void* d_out, int out_size, void* d_ws, size_t ws_size,
                              hipStream_t stream) {
    const float* feat   = (const float*)d_in[0];  // [B,C,H,W] fp32
    const int*   labels = (const int*)d_in[1];    // [B,H,W] int32
    const float* preds  = (const float*)d_in[2];  // [B,NCLS,H,W] fp32
    float* out = (float*)d_out;

    // workspace layout (all offsets 16B-aligned)
    unsigned char* pd = (unsigned char*)d_ws;                    // 262144 B
    int* slots = (int*)(pd + BB * NPIX);                         // 12288 ints
    unsigned* bandCounts = (unsigned*)(slots + NPAIR * MAXS);    // 768 uints
    unsigned* pairTotals = bandCounts + NPAIR * NBAND;           // 12 uints

    k_dargmax<<<NBAND * BB, 256, 0, stream>>>(preds, labels, pd, bandCounts);
    k_assign<<<NPAIR * NCHUNK, 256, 0, stream>>>(labels, pd, bandCounts, pairTotals, slots, out);
    k_gather<<<NOUT / 4 / 256, 256, 0, stream>>>(feat, slots, pairTotals, out);
}